// Round 2
// baseline (6761.066 us; speedup 1.0000x reference)
//
#include <hip/hip_runtime.h>
#include <cmath>

typedef unsigned short u16;
typedef __attribute__((ext_vector_type(8))) short bf16x8;
typedef __attribute__((ext_vector_type(4))) float f32x4;

#define NTOK 2048
#define DIM 768
#define NHEAD 12
#define SEQ 1024
#define FFD 3072
#define NLAYER 12
#define VOCAB 50257
#define VPAD 50304

__device__ __forceinline__ float bf2f(u16 u) {
    unsigned int x = ((unsigned int)u) << 16;
    float f;
    __builtin_memcpy(&f, &x, 4);
    return f;
}
__device__ __forceinline__ u16 f2bf(float f) {
    unsigned int x;
    __builtin_memcpy(&x, &f, 4);
    x = x + 0x7fffu + ((x >> 16) & 1u);
    return (u16)(x >> 16);
}

// x[row][d] = tok_emb[idx[row]][d] + pos_emb[row % 1024][d]   (f32 in, f32 out)
__global__ __launch_bounds__(256) void embed_kernel(const int* __restrict__ idx,
        const float* __restrict__ tok, const float* __restrict__ pos, float* __restrict__ x) {
    int row = blockIdx.x;
    int tk = idx[row];
    int p = row & (SEQ - 1);
    int t = threadIdx.x;
#pragma unroll
    for (int i = 0; i < 3; ++i) {
        int d = t + i * 256;
        x[(size_t)row * DIM + d] = tok[(size_t)tk * DIM + d] + pos[(size_t)p * DIM + d];
    }
}

// LayerNorm row of 768, f32 in -> bf16 out (g,b are f32)
__global__ __launch_bounds__(256) void ln_kernel(const float* __restrict__ x,
        const float* __restrict__ g, const float* __restrict__ b, u16* __restrict__ out) {
    int row = blockIdx.x;
    const float* xr = x + (size_t)row * DIM;
    int t = threadIdx.x;
    float v0 = xr[t], v1 = xr[t + 256], v2 = xr[t + 512];
    float s = v0 + v1 + v2;
#pragma unroll
    for (int o = 1; o < 64; o <<= 1) s += __shfl_xor(s, o);
    __shared__ float red[4], red2[4];
    if ((t & 63) == 0) red[t >> 6] = s;
    __syncthreads();
    float mean = (red[0] + red[1] + red[2] + red[3]) * (1.0f / 768.0f);
    float d0 = v0 - mean, d1 = v1 - mean, d2 = v2 - mean;
    float q = d0 * d0 + d1 * d1 + d2 * d2;
#pragma unroll
    for (int o = 1; o < 64; o <<= 1) q += __shfl_xor(q, o);
    if ((t & 63) == 0) red2[t >> 6] = q;
    __syncthreads();
    float var = (red2[0] + red2[1] + red2[2] + red2[3]) * (1.0f / 768.0f);
    float rstd = rsqrtf(var + 1e-5f);
    out[(size_t)row * DIM + t]       = f2bf(d0 * rstd * g[t]       + b[t]);
    out[(size_t)row * DIM + t + 256] = f2bf(d1 * rstd * g[t + 256] + b[t + 256]);
    out[(size_t)row * DIM + t + 512] = f2bf(d2 * rstd * g[t + 512] + b[t + 512]);
}

// src[K][N] f32 -> dst[Nout][K] bf16, zero-fill for n >= N. grid (Nout/64, K/64)
__global__ __launch_bounds__(256) void transpose_kernel(const float* __restrict__ src,
        u16* __restrict__ dst, int K, int N, int vecok) {
    __shared__ float Ts[64][65];
    int n0 = blockIdx.x * 64, k0 = blockIdx.y * 64;
    int tid = threadIdx.x;
#pragma unroll
    for (int it = 0; it < 4; ++it) {
        int u = tid + it * 256;          // 0..1023
        int kr = u >> 4, nc = (u & 15) * 4;
        int gn = n0 + nc;
        const float* sp = &src[(size_t)(k0 + kr) * N];
        float4 v;
        if (vecok) {
            v = *(const float4*)&sp[gn];
        } else {
            v.x = (gn + 0 < N) ? sp[gn + 0] : 0.f;
            v.y = (gn + 1 < N) ? sp[gn + 1] : 0.f;
            v.z = (gn + 2 < N) ? sp[gn + 2] : 0.f;
            v.w = (gn + 3 < N) ? sp[gn + 3] : 0.f;
        }
        Ts[kr][nc] = v.x; Ts[kr][nc + 1] = v.y; Ts[kr][nc + 2] = v.z; Ts[kr][nc + 3] = v.w;
    }
    __syncthreads();
#pragma unroll
    for (int it = 0; it < 2; ++it) {
        int u = tid + it * 256;          // 0..511
        int nr = u >> 3, kc = (u & 7) * 8;
        union { u16 s[8]; uint4 v; } tmp;
#pragma unroll
        for (int j = 0; j < 8; ++j) tmp.s[j] = f2bf(Ts[kc + j][nr]);
        *(uint4*)&dst[(size_t)(n0 + nr) * K + k0 + kc] = tmp.v;
    }
}

// C[M,N] = A[M,K](bf16) @ Bt[N,K]^T(bf16) + epilogue
// MODE 0: out f32 = acc              (bounds-checked col < N; LM head)
// MODE 1: out f32 = acc + bias + res (residual, in-place on x; bias f32)
// MODE 2: out bf16 = gelu(acc + bias)
// MODE 3: out bf16 = acc             (exact-fit grid, no check; QKV)
template <int MODE>
__global__ __launch_bounds__(256) void gemm_kernel(
        const u16* __restrict__ A, const u16* __restrict__ Bt,
        const float* __restrict__ bias, const float* __restrict__ res,
        float* __restrict__ outf, u16* __restrict__ outb,
        int M, int N, int K) {
    __shared__ __align__(16) u16 As[128 * 32];
    __shared__ __align__(16) u16 Bs[128 * 32];
    int m0 = blockIdx.y * 128, n0 = blockIdx.x * 128;
    int tid = threadIdx.x;
    int lane = tid & 63, wave = tid >> 6;
    int wm = (wave >> 1) * 64, wn = (wave & 1) * 64;
    int l15 = lane & 15, k8 = (lane >> 4) * 8;
    f32x4 acc[4][4];
#pragma unroll
    for (int i = 0; i < 4; ++i)
#pragma unroll
        for (int j = 0; j < 4; ++j) acc[i][j] = f32x4{0.f, 0.f, 0.f, 0.f};

    int arow = tid >> 2, acol = (tid & 3) * 8;
    for (int kk = 0; kk < K; kk += 32) {
        __syncthreads();
#pragma unroll
        for (int it = 0; it < 2; ++it) {
            int row = arow + it * 64;
            *(uint4*)&As[row * 32 + acol] = *(const uint4*)&A[(size_t)(m0 + row) * K + kk + acol];
            *(uint4*)&Bs[row * 32 + acol] = *(const uint4*)&Bt[(size_t)(n0 + row) * K + kk + acol];
        }
        __syncthreads();
        bf16x8 af[4], bv[4];
#pragma unroll
        for (int i = 0; i < 4; ++i) af[i] = *(const bf16x8*)&As[(wm + i * 16 + l15) * 32 + k8];
#pragma unroll
        for (int j = 0; j < 4; ++j) bv[j] = *(const bf16x8*)&Bs[(wn + j * 16 + l15) * 32 + k8];
#pragma unroll
        for (int i = 0; i < 4; ++i)
#pragma unroll
            for (int j = 0; j < 4; ++j)
                acc[i][j] = __builtin_amdgcn_mfma_f32_16x16x32_bf16(af[i], bv[j], acc[i][j], 0, 0, 0);
    }
    int r0 = (lane >> 4) * 4;
#pragma unroll
    for (int i = 0; i < 4; ++i) {
#pragma unroll
        for (int j = 0; j < 4; ++j) {
#pragma unroll
            for (int r = 0; r < 4; ++r) {
                int gm = m0 + wm + i * 16 + r0 + r;
                int gn = n0 + wn + j * 16 + l15;
                float v = acc[i][j][r];
                if (MODE == 0) {
                    if (gn < N) outf[(size_t)gm * N + gn] = v;
                } else if (MODE == 1) {
                    v += bias[gn] + res[(size_t)gm * N + gn];
                    outf[(size_t)gm * N + gn] = v;
                } else if (MODE == 2) {
                    v += bias[gn];
                    v = 0.5f * v * (1.0f + erff(v * 0.70710678118f));
                    outb[(size_t)gm * N + gn] = f2bf(v);
                } else {
                    outb[(size_t)gm * N + gn] = f2bf(v);
                }
            }
        }
    }
}

// flash attention: qkv [2048][2304] bf16 (q|k|v each 768 wide), y [2048][768] bf16
// grid (16 qtiles, 12 heads, 2 batch), block 256
__global__ __launch_bounds__(256) void attn_kernel(const u16* __restrict__ qkv, u16* __restrict__ y) {
    __shared__ float Qs[64][65];
    __shared__ float Ks[64][65];
    __shared__ float Ps[64][65];
    __shared__ __align__(16) u16 Vs[64][64];
    int qt = blockIdx.x, h = blockIdx.y, b = blockIdx.z;
    int tid = threadIdx.x;
    int r = tid >> 2, c4 = tid & 3;
#pragma unroll
    for (int it = 0; it < 2; ++it) {
        int u = tid + it * 256;
        int row = u >> 3, c8 = (u & 7) * 8;
        int gr = b * SEQ + qt * 64 + row;
        union { u16 s[8]; uint4 v; } tq;
        tq.v = *(const uint4*)&qkv[(size_t)gr * 2304 + h * 64 + c8];
#pragma unroll
        for (int j = 0; j < 8; ++j) Qs[row][c8 + j] = bf2f(tq.s[j]);
    }
    float m = -INFINITY, l = 0.f;
    float O[16];
#pragma unroll
    for (int j = 0; j < 16; ++j) O[j] = 0.f;
    int qp = qt * 64 + r;
    for (int kt = 0; kt <= qt; ++kt) {
        __syncthreads();
#pragma unroll
        for (int it = 0; it < 2; ++it) {
            int u = tid + it * 256;
            int row = u >> 3, c8 = (u & 7) * 8;
            int gr = b * SEQ + kt * 64 + row;
            union { u16 s[8]; uint4 v; } tk, tv;
            tk.v = *(const uint4*)&qkv[(size_t)gr * 2304 + 768 + h * 64 + c8];
            tv.v = *(const uint4*)&qkv[(size_t)gr * 2304 + 1536 + h * 64 + c8];
#pragma unroll
            for (int j = 0; j < 8; ++j) Ks[row][c8 + j] = bf2f(tk.s[j]);
            *(uint4*)&Vs[row][c8] = tv.v;
        }
        __syncthreads();
        float s[16];
#pragma unroll
        for (int j = 0; j < 16; ++j) s[j] = 0.f;
        for (int d = 0; d < 64; ++d) {
            float qd = Qs[r][d];
#pragma unroll
            for (int j = 0; j < 16; ++j) s[j] += qd * Ks[c4 * 16 + j][d];
        }
        float mloc = -INFINITY;
#pragma unroll
        for (int j = 0; j < 16; ++j) {
            int kp = kt * 64 + c4 * 16 + j;
            s[j] = (kp <= qp) ? s[j] * 0.125f : -INFINITY;
            mloc = fmaxf(mloc, s[j]);
        }
        mloc = fmaxf(mloc, __shfl_xor(mloc, 1));
        mloc = fmaxf(mloc, __shfl_xor(mloc, 2));
        float mnew = fmaxf(m, mloc);
        float alpha = __expf(m - mnew);
        float lloc = 0.f;
#pragma unroll
        for (int j = 0; j < 16; ++j) {
            float p = __expf(s[j] - mnew);
            Ps[r][c4 * 16 + j] = p;
            lloc += p;
        }
        lloc += __shfl_xor(lloc, 1);
        lloc += __shfl_xor(lloc, 2);
        l = l * alpha + lloc;
        m = mnew;
#pragma unroll
        for (int j = 0; j < 16; ++j) O[j] *= alpha;
        __syncthreads();
        for (int k = 0; k < 64; ++k) {
            float pk = Ps[r][k];
#pragma unroll
            for (int j = 0; j < 16; ++j) O[j] += pk * bf2f(Vs[k][c4 * 16 + j]);
        }
    }
    float inv = 1.0f / l;
    int gr = b * SEQ + qt * 64 + r;
#pragma unroll
    for (int j = 0; j < 16; ++j)
        y[(size_t)gr * DIM + h * 64 + c4 * 16 + j] = f2bf(O[j] * inv);
}

extern "C" void kernel_launch(void* const* d_in, const int* in_sizes, int n_in,
                              void* d_out, int out_size, void* d_ws, size_t ws_size,
                              hipStream_t stream) {
    (void)in_sizes; (void)n_in; (void)out_size; (void)ws_size;
    const int*   idx = (const int*)d_in[0];
    const float* tok = (const float*)d_in[1];
    const float* pos = (const float*)d_in[2];
    const float* Wq  = (const float*)d_in[3];
    const float* Wk  = (const float*)d_in[4];
    const float* Wv  = (const float*)d_in[5];
    const float* Wo  = (const float*)d_in[6];
    const float* bo  = (const float*)d_in[7];
    const float* g1  = (const float*)d_in[8];
    const float* b1  = (const float*)d_in[9];
    const float* Wf1 = (const float*)d_in[10];
    const float* bf1 = (const float*)d_in[11];
    const float* Wf2 = (const float*)d_in[12];
    const float* bf2 = (const float*)d_in[13];
    const float* g2  = (const float*)d_in[14];
    const float* b2  = (const float*)d_in[15];
    const float* gf  = (const float*)d_in[16];
    const float* bfb = (const float*)d_in[17];
    const float* Wlm = (const float*)d_in[18];

    char* ws = (char*)d_ws;
    float* x    = (float*)(ws + 0);          // 2048*768*4   = 6291456
    u16* hbf    = (u16*)(ws + 6291456);      // 2048*768*2   = 3145728
    u16* qkv    = (u16*)(ws + 9437184);      // 2048*2304*2  = 9437184
    u16* ybf    = (u16*)(ws + 18874368);     // 2048*768*2   = 3145728
    u16* abf    = (u16*)(ws + 22020096);     // 2048*3072*2  = 12582912
    u16* WtA    = (u16*)(ws + 34603008);     // 4.72M elems  = 9437184
    u16* Wtlm   = (u16*)(ws + 44040192);     // 50304*768*2  = 77266944

    embed_kernel<<<NTOK, 256, 0, stream>>>(idx, tok, pos, x);

    const int DD = DIM * DIM;       // 589824
    for (int l = 0; l < NLAYER; ++l) {
        // transpose Wq/Wk/Wv/Wo (f32 [K][N]) -> WtA (bf16 [N][K]); qkv fused rows 0..2303, then o
        transpose_kernel<<<dim3(12, 12), 256, 0, stream>>>(Wq + (size_t)l * DD, WtA,          DIM, DIM, 1);
        transpose_kernel<<<dim3(12, 12), 256, 0, stream>>>(Wk + (size_t)l * DD, WtA + DD,     DIM, DIM, 1);
        transpose_kernel<<<dim3(12, 12), 256, 0, stream>>>(Wv + (size_t)l * DD, WtA + 2 * DD, DIM, DIM, 1);
        transpose_kernel<<<dim3(12, 12), 256, 0, stream>>>(Wo + (size_t)l * DD, WtA + 3 * DD, DIM, DIM, 1);

        ln_kernel<<<NTOK, 256, 0, stream>>>(x, g1 + l * DIM, b1 + l * DIM, hbf);
        // fused QKV: [2048,768] @ [768,2304] -> qkv [2048,2304] bf16
        gemm_kernel<3><<<dim3(18, 16), 256, 0, stream>>>(hbf, WtA, nullptr, nullptr,
                                                         nullptr, qkv, NTOK, 3 * DIM, DIM);
        attn_kernel<<<dim3(16, NHEAD, 2), 256, 0, stream>>>(qkv, ybf);
        // out proj + bias + residual -> x (f32)
        gemm_kernel<1><<<dim3(6, 16), 256, 0, stream>>>(ybf, WtA + 3 * DD, bo + l * DIM, x,
                                                        x, nullptr, NTOK, DIM, DIM);
        // FFN weights
        transpose_kernel<<<dim3(48, 12), 256, 0, stream>>>(Wf1 + (size_t)l * DIM * FFD, WtA, DIM, FFD, 1);
        transpose_kernel<<<dim3(12, 48), 256, 0, stream>>>(Wf2 + (size_t)l * FFD * DIM, WtA + FFD * DIM, FFD, DIM, 1);

        ln_kernel<<<NTOK, 256, 0, stream>>>(x, g2 + l * DIM, b2 + l * DIM, hbf);
        gemm_kernel<2><<<dim3(24, 16), 256, 0, stream>>>(hbf, WtA, bf1 + l * FFD, nullptr,
                                                         nullptr, abf, NTOK, FFD, DIM);
        gemm_kernel<1><<<dim3(6, 16), 256, 0, stream>>>(abf, WtA + FFD * DIM, bf2 + l * DIM, x,
                                                        x, nullptr, NTOK, DIM, FFD);
    }

    ln_kernel<<<NTOK, 256, 0, stream>>>(x, gf, bfb, hbf);
    transpose_kernel<<<dim3(VPAD / 64, 12), 256, 0, stream>>>(Wlm, Wtlm, DIM, VOCAB, 0);
    // LM head: f32 logits straight to d_out
    gemm_kernel<0><<<dim3(VPAD / 128, 16), 256, 0, stream>>>(hbf, Wtlm, nullptr, nullptr,
                                                             (float*)d_out, nullptr, NTOK, VOCAB, DIM);
}